// Round 8
// baseline (308.350 us; speedup 1.0000x reference)
//
#include <hip/hip_runtime.h>

#define KS     11
#define HH     512
#define WW     512
#define OUTD   502         // HH - KS + 1
#define OH     67          // output rows per band
#define ROWS   77          // OH + KS - 1 = 7*11 (multiple of KS)
#define NBANDS 8           // 8*67 = 536 >= 502
#define SCOLS  128         // output cols per wave (64 lanes x 2)
#define NSTRIP 4           // 4*128 = 512 >= 502
#define NIMG   96          // N*C = 32*3
#define NACC   256         // max accumulator slots (used only if workspace fits)

// Self-halo streaming SSIM: ZERO cross-lane ops in the row loop.
//   R5-R7 post-mortem: dur tracks wave-rows at ~12.5 cyc per shuffle ->
//   the per-CU DS pipe (10 halo shfl_down + 4 emit shfl_xor per row) is
//   saturated; VALU real busy ~35%, HBM 18%. Fix: each lane loads its own
//   12-col window (overlapping float2s; neighbor bytes are L1 hits) and
//   convolves ALL FOUR quantities {s,d,s^2,d^2} for its 2 cols -- no halo
//   shuffle, no emit reunite. DS ops in loop: none.
//   Sum/difference algebra (absmax 0.0 verified R1-R7):
//     4 mu_x mu_y = ms^2-md^2   2(mu_x^2+mu_y^2) = ms^2+md^2
//     4 conv(xy)  = Sss-Sdd     2(conv x^2+y^2)  = Sss+Sdd
//   Register budget: acc 88 + window 24 + prefetch 24 + misc ~20 => ~160
//   VGPR, 3 waves/SIMD (= the 12 waves/CU we measured anyway). (64,2)
//   keeps the allocator relaxed (R1: tight bounds => scratch disaster).
__global__ __launch_bounds__(64, 2)
void ssim_main(const float* __restrict__ xg, const float* __restrict__ yg,
               const float* __restrict__ win, double* __restrict__ acc_out,
               const int accmask)
{
    const int lane  = threadIdx.x;            // 0..63
    const int bid   = blockIdx.x;
    const int strip = bid & (NSTRIP - 1);
    const int band  = (bid >> 2) % NBANDS;
    const int img   = bid / (NSTRIP * NBANDS);
    const int row0  = band * OH;
    const int bc    = strip * SCOLS + 2 * lane;   // lane's first output col

    // Recover 1D gaussian from the (normalized, rank-1) 2D window: row sums.
    // Symmetric: store g[0..5], fold index at compile time.
    float g[6];
    #pragma unroll
    for (int i = 0; i < 6; i++) {
        float s = 0.f;
        #pragma unroll
        for (int j = 0; j < KS; j++) s += win[i * KS + j];
        g[i] = s;
    }
#define G(j) g[(j) <= 5 ? (j) : 10 - (j)]

    // 6 clamped float2 col offsets covering the lane's 12-col input window.
    // Strip 3 tail lanes (window past col 511) clamp to col 510: finite
    // garbage, and every output needing those cols is gated (bc+c >= OUTD).
    int coff[6];
    #pragma unroll
    for (int k = 0; k < 6; k++) {
        int c = bc + 2 * k;
        coff[k] = (c > WW - 2) ? (WW - 2) : c;
    }

    const float* xi = xg + (size_t)img * (HH * WW);
    const float* yi = yg + (size_t)img * (HH * WW);

    // rotating vertical accumulators [q: 0=s 1=d 2=s2 3=d2][col][slot].
    // Slot emitted at row r is overwritten (mul, i==0) at row r+1.
    float acc[4][2][KS];
    #pragma unroll
    for (int q = 0; q < 4; q++)
        #pragma unroll
        for (int c = 0; c < 2; c++)
            #pragma unroll
            for (int s = 0; s < KS; s++) acc[q][c][s] = 0.f;

    float ssum = 0.f;
    const float C1x2 = 0.0002f;  // 2*(0.01)^2
    const float C2x2 = 0.0018f;  // 2*(0.03)^2

    // current-row quantities + next-row raw prefetch
    float sv[12], dv[12];
    float2 lx[6], ly[6];

    // prologue: row0 formed directly; row0+1 prefetched
    {
        const float* xr = xi + (size_t)row0 * WW;
        const float* yr = yi + (size_t)row0 * WW;
        #pragma unroll
        for (int k = 0; k < 6; k++) {
            float2 a = *(const float2*)(xr + coff[k]);
            float2 b = *(const float2*)(yr + coff[k]);
            sv[2 * k] = a.x + b.x; sv[2 * k + 1] = a.y + b.y;
            dv[2 * k] = a.x - b.x; dv[2 * k + 1] = a.y - b.y;
        }
        const float* xr1 = xi + (size_t)(row0 + 1) * WW;  // row0+1 <= 470, in range
        const float* yr1 = yi + (size_t)(row0 + 1) * WW;
        #pragma unroll
        for (int k = 0; k < 6; k++) {
            lx[k] = *(const float2*)(xr1 + coff[k]);
            ly[k] = *(const float2*)(yr1 + coff[k]);
        }
    }

    #pragma unroll 1
    for (int rb = 0; rb < ROWS / KS; rb++) {
        #pragma unroll
        for (int rr = 0; rr < KS; rr++) {
            const int r = rb * KS + rr;

            // ---- horizontal 11-tap conv, 2 cols x 4 quantities (rolling sq) ----
            float hs0 = 0.f, hs1 = 0.f, hd0 = 0.f, hd1 = 0.f;
            float hS0 = 0.f, hS1 = 0.f, hD0 = 0.f, hD1 = 0.f;
            float qs = sv[0] * sv[0];
            float qd = dv[0] * dv[0];
            #pragma unroll
            for (int j = 0; j < KS; j++) {
                const float gj  = G(j);
                const float qs1 = sv[j + 1] * sv[j + 1];
                const float qd1 = dv[j + 1] * dv[j + 1];
                hs0 = fmaf(gj, sv[j],     hs0);  hs1 = fmaf(gj, sv[j + 1], hs1);
                hd0 = fmaf(gj, dv[j],     hd0);  hd1 = fmaf(gj, dv[j + 1], hd1);
                hS0 = fmaf(gj, qs,        hS0);  hS1 = fmaf(gj, qs1,       hS1);
                hD0 = fmaf(gj, qd,        hD0);  hD1 = fmaf(gj, qd1,       hD1);
                qs = qs1; qd = qd1;
            }

            // ---- vertical accumulate; i==0 overwrites slot rr (emitted last row) ----
            {
                const float g0 = G(0);
                acc[0][0][rr] = g0 * hs0; acc[0][1][rr] = g0 * hs1;
                acc[1][0][rr] = g0 * hd0; acc[1][1][rr] = g0 * hd1;
                acc[2][0][rr] = g0 * hS0; acc[2][1][rr] = g0 * hS1;
                acc[3][0][rr] = g0 * hD0; acc[3][1][rr] = g0 * hD1;
            }
            #pragma unroll
            for (int i = 1; i < KS; i++) {
                const int slot = (rr - i + KS) % KS;
                const float gi = G(i);
                acc[0][0][slot] = fmaf(gi, hs0, acc[0][0][slot]);
                acc[0][1][slot] = fmaf(gi, hs1, acc[0][1][slot]);
                acc[1][0][slot] = fmaf(gi, hd0, acc[1][0][slot]);
                acc[1][1][slot] = fmaf(gi, hd1, acc[1][1][slot]);
                acc[2][0][slot] = fmaf(gi, hS0, acc[2][0][slot]);
                acc[2][1][slot] = fmaf(gi, hS1, acc[2][1][slot]);
                acc[3][0][slot] = fmaf(gi, hD0, acc[3][0][slot]);
                acc[3][1][slot] = fmaf(gi, hD1, acc[3][1][slot]);
            }

            // ---- emit completed output row jloc = r-10 (slot (rr+1)%11) ----
            // Lane holds all 4 quantities for its 2 cols: NO cross-lane ops.
            const int es   = (rr + 1) % KS;
            const int jloc = r - (KS - 1);
            if (jloc >= 0 && jloc < OH && (row0 + jloc) < OUTD) {
                #pragma unroll
                for (int c = 0; c < 2; c++) {
                    if (bc + c < OUTD) {
                        const float ms = acc[0][c][es], md = acc[1][c][es];
                        const float Ss = acc[2][c][es], Sd = acc[3][c][es];
                        const float a = ms * ms, b = md * md;
                        const float P = a - b;        // 4 mu_x mu_y
                        const float Q = a + b;        // 2(mu_x^2 + mu_y^2)
                        const float U = Ss - Sd;      // 4 conv(xy)
                        const float V = Ss + Sd;      // 2(conv x^2 + conv y^2)
                        const float num = (P + C1x2) * ((U - P) + C2x2);
                        const float den = (Q + C1x2) * ((V - Q) + C2x2);
                        float rc = __builtin_amdgcn_rcpf(den);
                        rc = rc * fmaf(-den, rc, 2.0f);   // one NR step: ~0.5 ulp
                        ssum = fmaf(num, rc, ssum);
                    }
                }
            }

            // ---- form next row's quantities from prefetch; prefetch row r+2 ----
            if (r + 1 < ROWS) {
                #pragma unroll
                for (int k = 0; k < 6; k++) {
                    sv[2 * k]     = lx[k].x + ly[k].x;
                    sv[2 * k + 1] = lx[k].y + ly[k].y;
                    dv[2 * k]     = lx[k].x - ly[k].x;
                    dv[2 * k + 1] = lx[k].y - ly[k].y;
                }
            }
            if (r + 2 < ROWS) {
                int gr = row0 + r + 2; if (gr > HH - 1) gr = HH - 1;
                const float* xr = xi + (size_t)gr * WW;
                const float* yr = yi + (size_t)gr * WW;
                #pragma unroll
                for (int k = 0; k < 6; k++) {
                    lx[k] = *(const float2*)(xr + coff[k]);
                    ly[k] = *(const float2*)(yr + coff[k]);
                }
            }
        }
    }

    // single-wave block: shuffle reduce (only DS use in the kernel), 1 atomic
    #pragma unroll
    for (int off = 32; off > 0; off >>= 1)
        ssum += __shfl_down(ssum, off);
    if (lane == 0)
        atomicAdd(&acc_out[bid & accmask], (double)ssum);
}

__global__ void ssim_finalize(const double* __restrict__ acc, float* __restrict__ out,
                              const int nacc)
{
    double s = 0.0;
    for (int i = threadIdx.x; i < nacc; i += 64) s += acc[i];
    #pragma unroll
    for (int off = 32; off > 0; off >>= 1)
        s += __shfl_down(s, off);
    if (threadIdx.x == 0)
        out[0] = (float)(s * (1.0 / 24192384.0));   // 96*502*502 outputs
}

extern "C" void kernel_launch(void* const* d_in, const int* in_sizes, int n_in,
                              void* d_out, int out_size, void* d_ws, size_t ws_size,
                              hipStream_t stream)
{
    const float* x   = (const float*)d_in[0];
    const float* y   = (const float*)d_in[1];
    const float* win = (const float*)d_in[2];
    float* out = (float*)d_out;
    double* acc = (double*)d_ws;

    // Never assume workspace size (R3 lesson): spread slots only if they fit.
    const int nacc = (ws_size >= NACC * sizeof(double)) ? NACC : 1;
    hipMemsetAsync(acc, 0, nacc * sizeof(double), stream);
    ssim_main<<<dim3(NIMG * NBANDS * NSTRIP), dim3(64), 0, stream>>>(
        x, y, win, acc, nacc - 1);
    ssim_finalize<<<dim3(1), dim3(64), 0, stream>>>(acc, out, nacc);
}